// Round 4
// baseline (2087.686 us; speedup 1.0000x reference)
//
#include <hip/hip_runtime.h>
#include <math.h>

#define IN_DIMC 300
#define MEMC    300
#define BBC     32
#define DDC     11
#define NNC     2047
#define KT_N    10          // K tiles of 32 (K padded 300->320)
#define NT_N    20          // N tiles of 16 (N padded 300->320)
#define KP      328         // LDS row stride in bf16 elems (656B)
#define NODE_M  64
#define LEAF_M  128

typedef __attribute__((ext_vector_type(8))) short bf16x8;   // 8 bf16 = 4 VGPRs
typedef __attribute__((ext_vector_type(4))) float f32x4;    // MFMA accumulator

// Packed bf16 weight fragments: [w][kt][nt][lane][8]; 1KB/fragment, 1.6MB total
__device__ __align__(16) unsigned short g_Wp[8][KT_N][NT_N][64][8];

__device__ __forceinline__ float fsig(float x)  { return 1.0f / (1.0f + __expf(-x)); }
__device__ __forceinline__ float ftanh_(float x){ return 2.0f / (1.0f + __expf(-2.0f * x)) - 1.0f; }
__device__ __forceinline__ unsigned short f2bf(float f) {   // RNE fp32 -> bf16
    unsigned int u = __float_as_uint(f);
    u += 0x7FFFu + ((u >> 16) & 1u);
    return (unsigned short)(u >> 16);
}
__device__ __forceinline__ ushort4 f2bf4(float4 v) {
    ushort4 r; r.x = f2bf(v.x); r.y = f2bf(v.y); r.z = f2bf(v.z); r.w = f2bf(v.w);
    return r;
}

// ---------------------------------------------------------------------------
// Pack 8 weight matrices (fp32 [K=300][N=300]) into bf16 B-fragment layout.
// WID: 0=ix 1=ih 2=fx 3=fh 4=ox 5=oh 6=ux 7=uh
// ---------------------------------------------------------------------------
__global__ void pack_w(const float* __restrict__ Wix, const float* __restrict__ Wih,
                       const float* __restrict__ Wfx, const float* __restrict__ Wfh,
                       const float* __restrict__ Wox, const float* __restrict__ Woh,
                       const float* __restrict__ Wux, const float* __restrict__ Wuh)
{
    int gid = blockIdx.x * blockDim.x + threadIdx.x;
    const int total = 8 * KT_N * NT_N * 64;
    if (gid >= total) return;
    int l  = gid & 63;
    int f  = gid >> 6;
    int nt = f % NT_N;
    int kt = (f / NT_N) % KT_N;
    int w  = f / (NT_N * KT_N);
    const float* Ws[8] = {Wix, Wih, Wfx, Wfh, Wox, Woh, Wux, Wuh};
    const float* src = Ws[w];
    int n  = nt * 16 + (l & 15);
    int k0 = kt * 32 + 8 * (l >> 4);
    unsigned short tmp[8];
#pragma unroll
    for (int i = 0; i < 8; ++i) {
        int k = k0 + i;
        float v = (n < MEMC && k < IN_DIMC) ? src[k * MEMC + n] : 0.0f;
        tmp[i] = f2bf(v);
    }
    *reinterpret_cast<uint4*>(&g_Wp[w][kt][nt][l][0]) = *reinterpret_cast<const uint4*>(tmp);
}

// ---------------------------------------------------------------------------
// Leaf level: 128 rows/block, 8 waves; wave owns 3 or 2 nt (SIMD-balanced).
// 8 A-fragments (mt) per wave -> 8 MFMA per weight-fragment load.
// ---------------------------------------------------------------------------
__global__ __launch_bounds__(512, 2)
void leaf_k(const float* __restrict__ embs,
            const float* __restrict__ bix, const float* __restrict__ bih,
            const float* __restrict__ box_, const float* __restrict__ boh,
            const float* __restrict__ bux, const float* __restrict__ buh,
            float* __restrict__ h, float* __restrict__ c)
{
    extern __shared__ __align__(16) unsigned short xs[];    // [LEAF_M][KP]
    const int L    = 1 << (DDC - 1);
    const int base = L - 1;
    const int tid  = threadIdx.x;
    const int row0 = blockIdx.x * LEAF_M;

    for (int idx = tid; idx < LEAF_M * 75; idx += 512) {
        int r = idx / 75, q = idx - 75 * r;
        int row = row0 + r;
        int b = row >> (DDC - 1);
        int off = row & (L - 1);
        const float4 v = *reinterpret_cast<const float4*>(
            &embs[((size_t)b * NNC + base + off) * IN_DIMC + 4 * q]);
        *reinterpret_cast<ushort4*>(&xs[r * KP + 4 * q]) = f2bf4(v);
    }
    for (int idx = tid; idx < LEAF_M * 7; idx += 512) {    // K-pad [300..328)
        int r = idx / 7, qq = idx - 7 * r;
        *reinterpret_cast<ushort4*>(&xs[r * KP + 300 + 4 * qq]) = make_ushort4(0, 0, 0, 0);
    }
    __syncthreads();

    const int lane = tid & 63;
    const int w    = tid >> 6;
    const int nPass = (w < 4) ? 3 : 2;

    for (int p = 0; p < nPass; ++p) {
        const int nt = (w < 4) ? (3 * w + p) : (12 + 2 * (w - 4) + p);
        f32x4 aI[8], aO[8], aU[8];
        const f32x4 zv = {0.f, 0.f, 0.f, 0.f};
#pragma unroll
        for (int m = 0; m < 8; ++m) { aI[m] = zv; aO[m] = zv; aU[m] = zv; }

#pragma unroll
        for (int kt = 0; kt < KT_N; ++kt) {
            bf16x8 ax[8];
#pragma unroll
            for (int m = 0; m < 8; ++m)
                ax[m] = *reinterpret_cast<const bf16x8*>(
                    &xs[(16 * m + (lane & 15)) * KP + kt * 32 + 8 * (lane >> 4)]);
            const bf16x8 wI = *reinterpret_cast<const bf16x8*>(&g_Wp[0][kt][nt][lane][0]);
            const bf16x8 wO = *reinterpret_cast<const bf16x8*>(&g_Wp[4][kt][nt][lane][0]);
            const bf16x8 wU = *reinterpret_cast<const bf16x8*>(&g_Wp[6][kt][nt][lane][0]);
#pragma unroll
            for (int m = 0; m < 8; ++m) {
                aI[m] = __builtin_amdgcn_mfma_f32_16x16x32_bf16(ax[m], wI, aI[m], 0, 0, 0);
                aO[m] = __builtin_amdgcn_mfma_f32_16x16x32_bf16(ax[m], wO, aO[m], 0, 0, 0);
                aU[m] = __builtin_amdgcn_mfma_f32_16x16x32_bf16(ax[m], wU, aU[m], 0, 0, 0);
            }
        }

        const int col = nt * 16 + (lane & 15);
        if (col < MEMC) {
            const float bI = bix[col] + bih[col];
            const float bO = box_[col] + boh[col];
            const float bU = bux[col] + buh[col];
#pragma unroll
            for (int m = 0; m < 8; ++m) {
#pragma unroll
                for (int r2 = 0; r2 < 4; ++r2) {
                    int row = row0 + 16 * m + 4 * (lane >> 4) + r2;
                    int b = row >> (DDC - 1);
                    int off = row & (L - 1);
                    size_t o = ((size_t)b * NNC + base + off) * (size_t)MEMC + col;
                    float ig = fsig(aI[m][r2] + bI);
                    float og = fsig(aO[m][r2] + bO);
                    float ug = ftanh_(aU[m][r2] + bU);
                    float cv = ig * ug;
                    c[o] = cv;
                    h[o] = og * ftanh_(cv);
                }
            }
        }
    }
}

// ---------------------------------------------------------------------------
// Internal level: 64 rows/block, 8 waves, mt=4; 6 accumulator streams:
//   x-phase: aI,aO,aU,aFX; h-phase: aI,aO,aU (hs), aFS (hs@Wfh), aF1 (h1@Wfh)
//   f1 = sig(aFX+aF1+bf); f2 = sig(aFX+(aFS-aF1)+bf)
// ---------------------------------------------------------------------------
__global__ __launch_bounds__(512, 2)
void node_k(const float* __restrict__ embs,
            const float* __restrict__ bix, const float* __restrict__ bih,
            const float* __restrict__ bfx, const float* __restrict__ bfh,
            const float* __restrict__ box_, const float* __restrict__ boh,
            const float* __restrict__ bux, const float* __restrict__ buh,
            float* __restrict__ h, float* __restrict__ c, int lvl, int rowsTotal)
{
    extern __shared__ __align__(16) unsigned short sm[];
    unsigned short* xs  = sm;                       // [NODE_M][KP]
    unsigned short* hss = sm + NODE_M * KP;
    unsigned short* h1s = sm + 2 * NODE_M * KP;

    const int L    = 1 << lvl;
    const int base = L - 1;
    const int tid  = threadIdx.x;
    const int row0 = blockIdx.x * NODE_M;

    for (int idx = tid; idx < NODE_M * 75; idx += 512) {
        int r = idx / 75, q = idx - 75 * r;
        int row = row0 + r;
        if (row < rowsTotal) {
            int b = row >> lvl;
            int off = row & (L - 1);
            int node = base + off;
            const float4 xv = *reinterpret_cast<const float4*>(
                &embs[((size_t)b * NNC + node) * IN_DIMC + 4 * q]);
            const float4 h1v = *reinterpret_cast<const float4*>(
                &h[((size_t)b * NNC + 2 * node + 1) * MEMC + 4 * q]);
            const float4 h2v = *reinterpret_cast<const float4*>(
                &h[((size_t)b * NNC + 2 * node + 2) * MEMC + 4 * q]);
            float4 hsv;
            hsv.x = h1v.x + h2v.x; hsv.y = h1v.y + h2v.y;
            hsv.z = h1v.z + h2v.z; hsv.w = h1v.w + h2v.w;
            *reinterpret_cast<ushort4*>(&xs [r * KP + 4 * q]) = f2bf4(xv);
            *reinterpret_cast<ushort4*>(&h1s[r * KP + 4 * q]) = f2bf4(h1v);
            *reinterpret_cast<ushort4*>(&hss[r * KP + 4 * q]) = f2bf4(hsv);
        } else {
            ushort4 z = make_ushort4(0, 0, 0, 0);
            *reinterpret_cast<ushort4*>(&xs [r * KP + 4 * q]) = z;
            *reinterpret_cast<ushort4*>(&h1s[r * KP + 4 * q]) = z;
            *reinterpret_cast<ushort4*>(&hss[r * KP + 4 * q]) = z;
        }
    }
    for (int idx = tid; idx < NODE_M * 7; idx += 512) {     // K-pad
        int r = idx / 7, qq = idx - 7 * r;
        ushort4 z = make_ushort4(0, 0, 0, 0);
        *reinterpret_cast<ushort4*>(&xs [r * KP + 300 + 4 * qq]) = z;
        *reinterpret_cast<ushort4*>(&h1s[r * KP + 300 + 4 * qq]) = z;
        *reinterpret_cast<ushort4*>(&hss[r * KP + 300 + 4 * qq]) = z;
    }
    __syncthreads();

    const int lane = tid & 63;
    const int w    = tid >> 6;
    const int nPass = (w < 4) ? 3 : 2;

    for (int p = 0; p < nPass; ++p) {
        const int nt = (w < 4) ? (3 * w + p) : (12 + 2 * (w - 4) + p);
        f32x4 aI[4], aO[4], aU[4], aFX[4], aFS[4], aF1[4];
        const f32x4 zv = {0.f, 0.f, 0.f, 0.f};
#pragma unroll
        for (int m = 0; m < 4; ++m) {
            aI[m] = zv; aO[m] = zv; aU[m] = zv; aFX[m] = zv; aFS[m] = zv; aF1[m] = zv;
        }

        // x-phase: 4 weight loads -> 16 MFMA per kt
#pragma unroll
        for (int kt = 0; kt < KT_N; ++kt) {
            bf16x8 ax[4];
#pragma unroll
            for (int m = 0; m < 4; ++m)
                ax[m] = *reinterpret_cast<const bf16x8*>(
                    &xs[(16 * m + (lane & 15)) * KP + kt * 32 + 8 * (lane >> 4)]);
            const bf16x8 wI = *reinterpret_cast<const bf16x8*>(&g_Wp[0][kt][nt][lane][0]);
            const bf16x8 wF = *reinterpret_cast<const bf16x8*>(&g_Wp[2][kt][nt][lane][0]);
            const bf16x8 wO = *reinterpret_cast<const bf16x8*>(&g_Wp[4][kt][nt][lane][0]);
            const bf16x8 wU = *reinterpret_cast<const bf16x8*>(&g_Wp[6][kt][nt][lane][0]);
#pragma unroll
            for (int m = 0; m < 4; ++m) {
                aI[m]  = __builtin_amdgcn_mfma_f32_16x16x32_bf16(ax[m], wI, aI[m],  0, 0, 0);
                aFX[m] = __builtin_amdgcn_mfma_f32_16x16x32_bf16(ax[m], wF, aFX[m], 0, 0, 0);
                aO[m]  = __builtin_amdgcn_mfma_f32_16x16x32_bf16(ax[m], wO, aO[m],  0, 0, 0);
                aU[m]  = __builtin_amdgcn_mfma_f32_16x16x32_bf16(ax[m], wU, aU[m],  0, 0, 0);
            }
        }
        // h-phase: 4 weight loads -> 20 MFMA per kt
#pragma unroll
        for (int kt = 0; kt < KT_N; ++kt) {
            bf16x8 ahs[4], ah1[4];
#pragma unroll
            for (int m = 0; m < 4; ++m) {
                ahs[m] = *reinterpret_cast<const bf16x8*>(
                    &hss[(16 * m + (lane & 15)) * KP + kt * 32 + 8 * (lane >> 4)]);
                ah1[m] = *reinterpret_cast<const bf16x8*>(
                    &h1s[(16 * m + (lane & 15)) * KP + kt * 32 + 8 * (lane >> 4)]);
            }
            const bf16x8 wI = *reinterpret_cast<const bf16x8*>(&g_Wp[1][kt][nt][lane][0]);
            const bf16x8 wF = *reinterpret_cast<const bf16x8*>(&g_Wp[3][kt][nt][lane][0]);
            const bf16x8 wO = *reinterpret_cast<const bf16x8*>(&g_Wp[5][kt][nt][lane][0]);
            const bf16x8 wU = *reinterpret_cast<const bf16x8*>(&g_Wp[7][kt][nt][lane][0]);
#pragma unroll
            for (int m = 0; m < 4; ++m) {
                aI[m]  = __builtin_amdgcn_mfma_f32_16x16x32_bf16(ahs[m], wI, aI[m],  0, 0, 0);
                aO[m]  = __builtin_amdgcn_mfma_f32_16x16x32_bf16(ahs[m], wO, aO[m],  0, 0, 0);
                aU[m]  = __builtin_amdgcn_mfma_f32_16x16x32_bf16(ahs[m], wU, aU[m],  0, 0, 0);
                aFS[m] = __builtin_amdgcn_mfma_f32_16x16x32_bf16(ahs[m], wF, aFS[m], 0, 0, 0);
                aF1[m] = __builtin_amdgcn_mfma_f32_16x16x32_bf16(ah1[m], wF, aF1[m], 0, 0, 0);
            }
        }

        const int col = nt * 16 + (lane & 15);
        if (col < MEMC) {
            const float bI = bix[col] + bih[col];
            const float bO = box_[col] + boh[col];
            const float bU = bux[col] + buh[col];
            const float bF = bfx[col] + bfh[col];
#pragma unroll
            for (int m = 0; m < 4; ++m) {
#pragma unroll
                for (int r2 = 0; r2 < 4; ++r2) {
                    int row = row0 + 16 * m + 4 * (lane >> 4) + r2;
                    if (row < rowsTotal) {
                        int b = row >> lvl;
                        int off = row & (L - 1);
                        int node = base + off;
                        size_t o  = ((size_t)b * NNC + node) * (size_t)MEMC + col;
                        size_t o1 = ((size_t)b * NNC + 2 * node + 1) * (size_t)MEMC + col;
                        size_t o2 = ((size_t)b * NNC + 2 * node + 2) * (size_t)MEMC + col;
                        float ig = fsig(aI[m][r2] + bI);
                        float og = fsig(aO[m][r2] + bO);
                        float ug = ftanh_(aU[m][r2] + bU);
                        float f1 = fsig(aFX[m][r2] + aF1[m][r2] + bF);
                        float f2 = fsig(aFX[m][r2] + (aFS[m][r2] - aF1[m][r2]) + bF);
                        float cn = ig * ug + f1 * c[o1] + f2 * c[o2];
                        c[o] = cn;
                        h[o] = og * ftanh_(cn);
                    }
                }
            }
        }
    }
}

// ---------------------------------------------------------------------------
extern "C" void kernel_launch(void* const* d_in, const int* in_sizes, int n_in,
                              void* d_out, int out_size, void* d_ws, size_t ws_size,
                              hipStream_t stream)
{
    const float* embs = (const float*)d_in[0];
    const float* Wix  = (const float*)d_in[1];
    const float* bix  = (const float*)d_in[2];
    const float* Wih  = (const float*)d_in[3];
    const float* bih  = (const float*)d_in[4];
    const float* Wfx  = (const float*)d_in[5];
    const float* bfx  = (const float*)d_in[6];
    const float* Wfh  = (const float*)d_in[7];
    const float* bfh  = (const float*)d_in[8];
    const float* Wox  = (const float*)d_in[9];
    const float* box_ = (const float*)d_in[10];
    const float* Woh  = (const float*)d_in[11];
    const float* boh  = (const float*)d_in[12];
    const float* Wux  = (const float*)d_in[13];
    const float* bux  = (const float*)d_in[14];
    const float* Wuh  = (const float*)d_in[15];
    const float* buh  = (const float*)d_in[16];

    float* h = (float*)d_out;   // (B, N, 300) fp32
    float* c = (float*)d_ws;    // (B, N, 300) fp32 scratch

    const int leafLds = LEAF_M * KP * 2;        // 83,968 B
    const int nodeLds = 3 * NODE_M * KP * 2;    // 125,952 B
    (void)hipFuncSetAttribute((const void*)leaf_k,
                              hipFuncAttributeMaxDynamicSharedMemorySize, leafLds);
    (void)hipFuncSetAttribute((const void*)node_k,
                              hipFuncAttributeMaxDynamicSharedMemorySize, nodeLds);

    {   // pack weights
        const int total = 8 * KT_N * NT_N * 64;
        pack_w<<<(total + 255) / 256, 256, 0, stream>>>(Wix, Wih, Wfx, Wfh, Wox, Woh, Wux, Wuh);
    }

    {   // leaf level: 32768 rows / 128 = 256 blocks
        int rows = BBC << (DDC - 1);
        leaf_k<<<rows / LEAF_M, 512, leafLds, stream>>>(
            embs, bix, bih, box_, boh, bux, buh, h, c);
    }

    for (int lvl = DDC - 2; lvl >= 0; --lvl) {
        int rows = BBC << lvl;
        int blocks = (rows + NODE_M - 1) / NODE_M;
        node_k<<<blocks, 512, nodeLds, stream>>>(
            embs, bix, bih, bfx, bfh, box_, boh, bux, buh, h, c, lvl, rows);
    }
}

// Round 5
// 1129.226 us; speedup vs baseline: 1.8488x; 1.8488x over previous
//
#include <hip/hip_runtime.h>
#include <math.h>

#define IN_DIMC 300
#define MEMC    300
#define BBC     32
#define DDC     11
#define NNC     2047
#define KT_N    10          // K tiles of 32 (K padded 300->320)
#define NT_USED 19          // ceil(300/16); tile 19 (cols 304..319) is pure pad
#define NT_PAD  20
#define KP      328         // LDS row stride in bf16 elems (656B)
#define NODE_M  32
#define LEAF_M  64
#define NTHR    512

typedef __attribute__((ext_vector_type(8))) short bf16x8;   // 8 bf16 = 4 VGPRs
typedef __attribute__((ext_vector_type(4))) float f32x4;    // MFMA accumulator

// Packed bf16 weight fragments: [w][kt][nt][lane][8]; 1KB per (w,kt,nt) fragment
__device__ __align__(16) unsigned short g_Wp[8][KT_N][NT_PAD][64][8];

__device__ __forceinline__ float fsig(float x)  { return 1.0f / (1.0f + __expf(-x)); }
__device__ __forceinline__ float ftanh_(float x){ return 2.0f / (1.0f + __expf(-2.0f * x)) - 1.0f; }
__device__ __forceinline__ unsigned short f2bf(float f) {   // RNE fp32 -> bf16
    unsigned int u = __float_as_uint(f);
    u += 0x7FFFu + ((u >> 16) & 1u);
    return (unsigned short)(u >> 16);
}
__device__ __forceinline__ ushort4 f2bf4(float4 v) {
    ushort4 r; r.x = f2bf(v.x); r.y = f2bf(v.y); r.z = f2bf(v.z); r.w = f2bf(v.w);
    return r;
}

// ---------------------------------------------------------------------------
// Pack 8 weight matrices (fp32 [K=300][N=300]) into bf16 B-fragment layout.
// WID: 0=ix 1=ih 2=fx 3=fh 4=ox 5=oh 6=ux 7=uh
// ---------------------------------------------------------------------------
__global__ void pack_w(const float* __restrict__ Wix, const float* __restrict__ Wih,
                       const float* __restrict__ Wfx, const float* __restrict__ Wfh,
                       const float* __restrict__ Wox, const float* __restrict__ Woh,
                       const float* __restrict__ Wux, const float* __restrict__ Wuh)
{
    int gid = blockIdx.x * blockDim.x + threadIdx.x;
    const int total = 8 * KT_N * NT_PAD * 64;
    if (gid >= total) return;
    int l  = gid & 63;
    int f  = gid >> 6;
    int nt = f % NT_PAD;
    int kt = (f / NT_PAD) % KT_N;
    int w  = f / (NT_PAD * KT_N);
    const float* Ws[8] = {Wix, Wih, Wfx, Wfh, Wox, Woh, Wux, Wuh};
    const float* src = Ws[w];
    int n  = nt * 16 + (l & 15);
    int k0 = kt * 32 + 8 * (l >> 4);
    unsigned short tmp[8];
#pragma unroll
    for (int i = 0; i < 8; ++i) {
        int k = k0 + i;
        float v = (n < MEMC && k < IN_DIMC) ? src[k * MEMC + n] : 0.0f;
        tmp[i] = f2bf(v);
    }
    *reinterpret_cast<uint4*>(&g_Wp[w][kt][nt][l][0]) = *reinterpret_cast<const uint4*>(tmp);
}

// ---------------------------------------------------------------------------
// Leaf level: 64 rows/block, 8 waves, m=4 A-frags; wave w does nt = w, w+8, w+16.
// LDS 42KB -> 3 blocks LDS-wise; VGPR<=128 -> 2 blocks (16 waves) resident.
// ---------------------------------------------------------------------------
__global__ __launch_bounds__(512, 4)
void leaf_k(const float* __restrict__ embs,
            const float* __restrict__ bix, const float* __restrict__ bih,
            const float* __restrict__ box_, const float* __restrict__ boh,
            const float* __restrict__ bux, const float* __restrict__ buh,
            float* __restrict__ h, float* __restrict__ c)
{
    __shared__ __align__(16) unsigned short xs[LEAF_M * KP];
    const int L    = 1 << (DDC - 1);
    const int base = L - 1;
    const int tid  = threadIdx.x;
    const int row0 = blockIdx.x * LEAF_M;

    for (int idx = tid; idx < LEAF_M * 75; idx += NTHR) {
        int r = idx / 75, q = idx - 75 * r;
        int row = row0 + r;
        int b = row >> (DDC - 1);
        int off = row & (L - 1);
        const float4 v = *reinterpret_cast<const float4*>(
            &embs[((size_t)b * NNC + base + off) * IN_DIMC + 4 * q]);
        *reinterpret_cast<ushort4*>(&xs[r * KP + 4 * q]) = f2bf4(v);
    }
    for (int idx = tid; idx < LEAF_M * 7; idx += NTHR) {    // K-pad [300..328)
        int r = idx / 7, qq = idx - 7 * r;
        *reinterpret_cast<ushort4*>(&xs[r * KP + 300 + 4 * qq]) = make_ushort4(0, 0, 0, 0);
    }
    __syncthreads();

    const int lane = tid & 63;
    const int wv   = tid >> 6;

    for (int nt = wv; nt < NT_USED; nt += 8) {
        f32x4 aI[4], aO[4], aU[4];
        const f32x4 zv = {0.f, 0.f, 0.f, 0.f};
#pragma unroll
        for (int m = 0; m < 4; ++m) { aI[m] = zv; aO[m] = zv; aU[m] = zv; }

#pragma unroll
        for (int kt = 0; kt < KT_N; ++kt) {
            bf16x8 ax[4];
#pragma unroll
            for (int m = 0; m < 4; ++m)
                ax[m] = *reinterpret_cast<const bf16x8*>(
                    &xs[(16 * m + (lane & 15)) * KP + kt * 32 + 8 * (lane >> 4)]);
            const bf16x8 wI = *reinterpret_cast<const bf16x8*>(&g_Wp[0][kt][nt][lane][0]);
            const bf16x8 wO = *reinterpret_cast<const bf16x8*>(&g_Wp[4][kt][nt][lane][0]);
            const bf16x8 wU = *reinterpret_cast<const bf16x8*>(&g_Wp[6][kt][nt][lane][0]);
#pragma unroll
            for (int m = 0; m < 4; ++m) {
                aI[m] = __builtin_amdgcn_mfma_f32_16x16x32_bf16(ax[m], wI, aI[m], 0, 0, 0);
                aO[m] = __builtin_amdgcn_mfma_f32_16x16x32_bf16(ax[m], wO, aO[m], 0, 0, 0);
                aU[m] = __builtin_amdgcn_mfma_f32_16x16x32_bf16(ax[m], wU, aU[m], 0, 0, 0);
            }
        }

        const int col = nt * 16 + (lane & 15);
        if (col < MEMC) {
            const float bI = bix[col] + bih[col];
            const float bO = box_[col] + boh[col];
            const float bU = bux[col] + buh[col];
#pragma unroll
            for (int m = 0; m < 4; ++m) {
#pragma unroll
                for (int r2 = 0; r2 < 4; ++r2) {
                    int row = row0 + 16 * m + 4 * (lane >> 4) + r2;
                    int b = row >> (DDC - 1);
                    int off = row & (L - 1);
                    size_t o = ((size_t)b * NNC + base + off) * (size_t)MEMC + col;
                    float ig = fsig(aI[m][r2] + bI);
                    float og = fsig(aO[m][r2] + bO);
                    float ug = ftanh_(aU[m][r2] + bU);
                    float cv = ig * ug;
                    c[o] = cv;
                    h[o] = og * ftanh_(cv);
                }
            }
        }
    }
}

// ---------------------------------------------------------------------------
// Internal level: 32 rows/block, m=2. h-sum done via MFMA linearity:
//   i,o,u accumulate h1-part + h2-part; f: x-part into aF1, copied to aF2,
//   then aF1 += h1@Wfh, aF2 += h2@Wfh.
// blockIdx.y selects an nt-group (G=5 for small levels) for extra parallelism.
// ---------------------------------------------------------------------------
__global__ __launch_bounds__(512, 4)
void node_k(const float* __restrict__ embs,
            const float* __restrict__ bix, const float* __restrict__ bih,
            const float* __restrict__ bfx, const float* __restrict__ bfh,
            const float* __restrict__ box_, const float* __restrict__ boh,
            const float* __restrict__ bux, const float* __restrict__ buh,
            float* __restrict__ h, float* __restrict__ c,
            int lvl, int rowsTotal, int ntPerG)
{
    __shared__ __align__(16) unsigned short xs [NODE_M * KP];
    __shared__ __align__(16) unsigned short h1s[NODE_M * KP];
    __shared__ __align__(16) unsigned short h2s[NODE_M * KP];

    const int L    = 1 << lvl;
    const int base = L - 1;
    const int tid  = threadIdx.x;
    const int row0 = blockIdx.x * NODE_M;

    for (int idx = tid; idx < NODE_M * 75; idx += NTHR) {
        int r = idx / 75, q = idx - 75 * r;
        int row = row0 + r;
        if (row < rowsTotal) {
            int b = row >> lvl;
            int off = row & (L - 1);
            int node = base + off;
            const float4 xv = *reinterpret_cast<const float4*>(
                &embs[((size_t)b * NNC + node) * IN_DIMC + 4 * q]);
            const float4 h1v = *reinterpret_cast<const float4*>(
                &h[((size_t)b * NNC + 2 * node + 1) * MEMC + 4 * q]);
            const float4 h2v = *reinterpret_cast<const float4*>(
                &h[((size_t)b * NNC + 2 * node + 2) * MEMC + 4 * q]);
            *reinterpret_cast<ushort4*>(&xs [r * KP + 4 * q]) = f2bf4(xv);
            *reinterpret_cast<ushort4*>(&h1s[r * KP + 4 * q]) = f2bf4(h1v);
            *reinterpret_cast<ushort4*>(&h2s[r * KP + 4 * q]) = f2bf4(h2v);
        } else {
            ushort4 z = make_ushort4(0, 0, 0, 0);
            *reinterpret_cast<ushort4*>(&xs [r * KP + 4 * q]) = z;
            *reinterpret_cast<ushort4*>(&h1s[r * KP + 4 * q]) = z;
            *reinterpret_cast<ushort4*>(&h2s[r * KP + 4 * q]) = z;
        }
    }
    for (int idx = tid; idx < NODE_M * 7; idx += NTHR) {    // K-pad
        int r = idx / 7, qq = idx - 7 * r;
        ushort4 z = make_ushort4(0, 0, 0, 0);
        *reinterpret_cast<ushort4*>(&xs [r * KP + 300 + 4 * qq]) = z;
        *reinterpret_cast<ushort4*>(&h1s[r * KP + 300 + 4 * qq]) = z;
        *reinterpret_cast<ushort4*>(&h2s[r * KP + 300 + 4 * qq]) = z;
    }
    __syncthreads();

    const int lane   = tid & 63;
    const int wv     = tid >> 6;
    const int ntBase = blockIdx.y * ntPerG;
    int ntEnd = ntBase + ntPerG;
    if (ntEnd > NT_USED) ntEnd = NT_USED;

    for (int nt = ntBase + wv; nt < ntEnd; nt += 8) {
        f32x4 aI[2], aO[2], aU[2], aF1[2], aF2[2];
        const f32x4 zv = {0.f, 0.f, 0.f, 0.f};
#pragma unroll
        for (int m = 0; m < 2; ++m) { aI[m] = zv; aO[m] = zv; aU[m] = zv; aF1[m] = zv; }

        // x-phase: f's x-part accumulates into aF1
#pragma unroll
        for (int kt = 0; kt < KT_N; ++kt) {
            bf16x8 ax[2];
#pragma unroll
            for (int m = 0; m < 2; ++m)
                ax[m] = *reinterpret_cast<const bf16x8*>(
                    &xs[(16 * m + (lane & 15)) * KP + kt * 32 + 8 * (lane >> 4)]);
            const bf16x8 wI = *reinterpret_cast<const bf16x8*>(&g_Wp[0][kt][nt][lane][0]);
            const bf16x8 wF = *reinterpret_cast<const bf16x8*>(&g_Wp[2][kt][nt][lane][0]);
            const bf16x8 wO = *reinterpret_cast<const bf16x8*>(&g_Wp[4][kt][nt][lane][0]);
            const bf16x8 wU = *reinterpret_cast<const bf16x8*>(&g_Wp[6][kt][nt][lane][0]);
#pragma unroll
            for (int m = 0; m < 2; ++m) {
                aI[m]  = __builtin_amdgcn_mfma_f32_16x16x32_bf16(ax[m], wI, aI[m],  0, 0, 0);
                aF1[m] = __builtin_amdgcn_mfma_f32_16x16x32_bf16(ax[m], wF, aF1[m], 0, 0, 0);
                aO[m]  = __builtin_amdgcn_mfma_f32_16x16x32_bf16(ax[m], wO, aO[m],  0, 0, 0);
                aU[m]  = __builtin_amdgcn_mfma_f32_16x16x32_bf16(ax[m], wU, aU[m],  0, 0, 0);
            }
        }
#pragma unroll
        for (int m = 0; m < 2; ++m) aF2[m] = aF1[m];        // share x-part

        // h-phase: i,o,u get h1-part + h2-part (linearity); f1 gets h1, f2 gets h2
#pragma unroll
        for (int kt = 0; kt < KT_N; ++kt) {
            bf16x8 a1[2], a2[2];
#pragma unroll
            for (int m = 0; m < 2; ++m) {
                a1[m] = *reinterpret_cast<const bf16x8*>(
                    &h1s[(16 * m + (lane & 15)) * KP + kt * 32 + 8 * (lane >> 4)]);
                a2[m] = *reinterpret_cast<const bf16x8*>(
                    &h2s[(16 * m + (lane & 15)) * KP + kt * 32 + 8 * (lane >> 4)]);
            }
            const bf16x8 wI = *reinterpret_cast<const bf16x8*>(&g_Wp[1][kt][nt][lane][0]);
            const bf16x8 wF = *reinterpret_cast<const bf16x8*>(&g_Wp[3][kt][nt][lane][0]);
            const bf16x8 wO = *reinterpret_cast<const bf16x8*>(&g_Wp[5][kt][nt][lane][0]);
            const bf16x8 wU = *reinterpret_cast<const bf16x8*>(&g_Wp[7][kt][nt][lane][0]);
#pragma unroll
            for (int m = 0; m < 2; ++m) {
                aI[m]  = __builtin_amdgcn_mfma_f32_16x16x32_bf16(a1[m], wI, aI[m],  0, 0, 0);
                aI[m]  = __builtin_amdgcn_mfma_f32_16x16x32_bf16(a2[m], wI, aI[m],  0, 0, 0);
                aO[m]  = __builtin_amdgcn_mfma_f32_16x16x32_bf16(a1[m], wO, aO[m],  0, 0, 0);
                aO[m]  = __builtin_amdgcn_mfma_f32_16x16x32_bf16(a2[m], wO, aO[m],  0, 0, 0);
                aU[m]  = __builtin_amdgcn_mfma_f32_16x16x32_bf16(a1[m], wU, aU[m],  0, 0, 0);
                aU[m]  = __builtin_amdgcn_mfma_f32_16x16x32_bf16(a2[m], wU, aU[m],  0, 0, 0);
                aF1[m] = __builtin_amdgcn_mfma_f32_16x16x32_bf16(a1[m], wF, aF1[m], 0, 0, 0);
                aF2[m] = __builtin_amdgcn_mfma_f32_16x16x32_bf16(a2[m], wF, aF2[m], 0, 0, 0);
            }
        }

        const int col = nt * 16 + (lane & 15);
        if (col < MEMC) {
            const float bI = bix[col] + bih[col];
            const float bO = box_[col] + boh[col];
            const float bU = bux[col] + buh[col];
            const float bF = bfx[col] + bfh[col];
#pragma unroll
            for (int m = 0; m < 2; ++m) {
#pragma unroll
                for (int r2 = 0; r2 < 4; ++r2) {
                    int row = row0 + 16 * m + 4 * (lane >> 4) + r2;
                    if (row < rowsTotal) {
                        int b = row >> lvl;
                        int off = row & (L - 1);
                        int node = base + off;
                        size_t o  = ((size_t)b * NNC + node) * (size_t)MEMC + col;
                        size_t o1 = ((size_t)b * NNC + 2 * node + 1) * (size_t)MEMC + col;
                        size_t o2 = ((size_t)b * NNC + 2 * node + 2) * (size_t)MEMC + col;
                        float ig = fsig(aI[m][r2] + bI);
                        float og = fsig(aO[m][r2] + bO);
                        float ug = ftanh_(aU[m][r2] + bU);
                        float f1 = fsig(aF1[m][r2] + bF);
                        float f2 = fsig(aF2[m][r2] + bF);
                        float cn = ig * ug + f1 * c[o1] + f2 * c[o2];
                        c[o] = cn;
                        h[o] = og * ftanh_(cn);
                    }
                }
            }
        }
    }
}

// ---------------------------------------------------------------------------
extern "C" void kernel_launch(void* const* d_in, const int* in_sizes, int n_in,
                              void* d_out, int out_size, void* d_ws, size_t ws_size,
                              hipStream_t stream)
{
    const float* embs = (const float*)d_in[0];
    const float* Wix  = (const float*)d_in[1];
    const float* bix  = (const float*)d_in[2];
    const float* Wih  = (const float*)d_in[3];
    const float* bih  = (const float*)d_in[4];
    const float* Wfx  = (const float*)d_in[5];
    const float* bfx  = (const float*)d_in[6];
    const float* Wfh  = (const float*)d_in[7];
    const float* bfh  = (const float*)d_in[8];
    const float* Wox  = (const float*)d_in[9];
    const float* box_ = (const float*)d_in[10];
    const float* Woh  = (const float*)d_in[11];
    const float* boh  = (const float*)d_in[12];
    const float* Wux  = (const float*)d_in[13];
    const float* bux  = (const float*)d_in[14];
    const float* Wuh  = (const float*)d_in[15];
    const float* buh  = (const float*)d_in[16];

    float* h = (float*)d_out;   // (B, N, 300) fp32
    float* c = (float*)d_ws;    // (B, N, 300) fp32 scratch

    {   // pack weights to bf16 fragments
        const int total = 8 * KT_N * NT_PAD * 64;
        pack_w<<<(total + 255) / 256, 256, 0, stream>>>(Wix, Wih, Wfx, Wfh, Wox, Woh, Wux, Wuh);
    }

    {   // leaf level: 32768 rows / 64 = 512 blocks
        int rows = BBC << (DDC - 1);
        leaf_k<<<rows / LEAF_M, NTHR, 0, stream>>>(
            embs, bix, bih, box_, boh, bux, buh, h, c);
    }

    for (int lvl = DDC - 2; lvl >= 0; --lvl) {
        int rows = BBC << lvl;
        int blocksX = (rows + NODE_M - 1) / NODE_M;
        int G, ntPerG;
        if (lvl >= 6) { G = 1; ntPerG = NT_USED; }   // big levels: blocks plentiful
        else         { G = 5; ntPerG = 4; }          // small levels: split columns
        node_k<<<dim3(blocksX, G), NTHR, 0, stream>>>(
            embs, bix, bih, bfx, bfh, box_, boh, bux, buh, h, c, lvl, rows, ntPerG);
    }
}

// Round 6
// 511.057 us; speedup vs baseline: 4.0850x; 2.2096x over previous
//
#include <hip/hip_runtime.h>
#include <math.h>

#define IN_DIMC 300
#define MEMC    300
#define BBC     32
#define DDC     11
#define NNC     2047
#define KT_N    10          // K tiles of 32 (K padded 300->320)
#define NT_USED 19          // ceil(300/16)
#define NT_PAD  20
#define KP      328         // LDS row stride in bf16 elems (656B, bank-safe, 16B-aligned rows)
#define NODE_M  32
#define LEAF_M  64
#define NTHR    512
#define GP      132         // gate/out staging col stride (floats), bank-safe

typedef __attribute__((ext_vector_type(8))) short bf16x8;   // 8 bf16 = 4 VGPRs
typedef __attribute__((ext_vector_type(4))) float f32x4;

// Packed bf16 weight fragments: [w][kt][nt][lane][8]
__device__ __align__(16) unsigned short g_Wp[8][KT_N][NT_PAD][64][8];

__device__ __forceinline__ float fsig(float x)  { return 1.0f / (1.0f + __expf(-x)); }
__device__ __forceinline__ float ftanh_(float x){ return 2.0f / (1.0f + __expf(-2.0f * x)) - 1.0f; }
__device__ __forceinline__ unsigned short f2bf(float f) {   // RNE fp32 -> bf16
    unsigned int u = __float_as_uint(f);
    u += 0x7FFFu + ((u >> 16) & 1u);
    return (unsigned short)(u >> 16);
}
__device__ __forceinline__ ushort4 f2bf4(float4 v) {
    ushort4 r; r.x = f2bf(v.x); r.y = f2bf(v.y); r.z = f2bf(v.z); r.w = f2bf(v.w);
    return r;
}

// ---------------------------------------------------------------------------
// Pack 8 weight matrices (fp32 [K=300][N=300]) into bf16 B-fragment layout.
// WID: 0=ix 1=ih 2=fx 3=fh 4=ox 5=oh 6=ux 7=uh
// ---------------------------------------------------------------------------
__global__ void pack_w(const float* __restrict__ Wix, const float* __restrict__ Wih,
                       const float* __restrict__ Wfx, const float* __restrict__ Wfh,
                       const float* __restrict__ Wox, const float* __restrict__ Woh,
                       const float* __restrict__ Wux, const float* __restrict__ Wuh)
{
    int gid = blockIdx.x * blockDim.x + threadIdx.x;
    const int total = 8 * KT_N * NT_PAD * 64;
    if (gid >= total) return;
    int l  = gid & 63;
    int f  = gid >> 6;
    int nt = f % NT_PAD;
    int kt = (f / NT_PAD) % KT_N;
    int w  = f / (NT_PAD * KT_N);
    const float* Ws[8] = {Wix, Wih, Wfx, Wfh, Wox, Woh, Wux, Wuh};
    const float* src = Ws[w];
    int n  = nt * 16 + (l & 15);
    int k0 = kt * 32 + 8 * (l >> 4);
    unsigned short tmp[8];
#pragma unroll
    for (int i = 0; i < 8; ++i) {
        int k = k0 + i;
        float v = (n < MEMC && k < IN_DIMC) ? src[k * MEMC + n] : 0.0f;
        tmp[i] = f2bf(v);
    }
    *reinterpret_cast<uint4*>(&g_Wp[w][kt][nt][l][0]) = *reinterpret_cast<const uint4*>(tmp);
}

// ---------------------------------------------------------------------------
// Leaf: 64 rows/block. Wave wv handles nt = 8k+wv (k=0..2). Epilogue staged in
// LDS then written cooperatively as float4 full-row segments (coalesced).
// ---------------------------------------------------------------------------
__global__ __launch_bounds__(512, 4)
void leaf_k(const float* __restrict__ embs,
            const float* __restrict__ bix, const float* __restrict__ bih,
            const float* __restrict__ box_, const float* __restrict__ boh,
            const float* __restrict__ bux, const float* __restrict__ buh,
            float* __restrict__ h, float* __restrict__ c)
{
    __shared__ __align__(16) unsigned short xs[LEAF_M * KP];
    __shared__ __align__(16) float chF[2][16][GP];

    const int L    = 1 << (DDC - 1);
    const int base = L - 1;
    const int tid  = threadIdx.x;
    const int row0 = blockIdx.x * LEAF_M;

    for (int idx = tid; idx < LEAF_M * 75; idx += NTHR) {
        int r = idx / 75, q = idx - 75 * r;
        int row = row0 + r;
        int b = row >> (DDC - 1);
        int off = row & (L - 1);
        const float4 v = *reinterpret_cast<const float4*>(
            &embs[((size_t)b * NNC + base + off) * IN_DIMC + 4 * q]);
        *reinterpret_cast<ushort4*>(&xs[r * KP + 4 * q]) = f2bf4(v);
    }
    for (int idx = tid; idx < LEAF_M * 7; idx += NTHR) {
        int r = idx / 7, qq = idx - 7 * r;
        *reinterpret_cast<ushort4*>(&xs[r * KP + 300 + 4 * qq]) = make_ushort4(0, 0, 0, 0);
    }
    __syncthreads();

    const int lane = tid & 63;
    const int l15  = lane & 15;
    const int lhi  = lane >> 4;
    const int wv   = tid >> 6;

    for (int k = 0; k < 3; ++k) {
        const int nt = 8 * k + wv;
        const bool ntv = (nt < NT_USED);
        f32x4 cv_[4], hv_[4];
        if (ntv) {
            f32x4 aI[4], aO[4], aU[4];
            const f32x4 zv = {0.f, 0.f, 0.f, 0.f};
#pragma unroll
            for (int m = 0; m < 4; ++m) { aI[m] = zv; aO[m] = zv; aU[m] = zv; }
#pragma unroll
            for (int kt = 0; kt < KT_N; ++kt) {
                bf16x8 ax[4];
#pragma unroll
                for (int m = 0; m < 4; ++m)
                    ax[m] = *reinterpret_cast<const bf16x8*>(
                        &xs[(16 * m + l15) * KP + kt * 32 + 8 * lhi]);
                const bf16x8 wI = *reinterpret_cast<const bf16x8*>(&g_Wp[0][kt][nt][lane][0]);
                const bf16x8 wO = *reinterpret_cast<const bf16x8*>(&g_Wp[4][kt][nt][lane][0]);
                const bf16x8 wU = *reinterpret_cast<const bf16x8*>(&g_Wp[6][kt][nt][lane][0]);
#pragma unroll
                for (int m = 0; m < 4; ++m) {
                    aI[m] = __builtin_amdgcn_mfma_f32_16x16x32_bf16(ax[m], wI, aI[m], 0, 0, 0);
                    aO[m] = __builtin_amdgcn_mfma_f32_16x16x32_bf16(ax[m], wO, aO[m], 0, 0, 0);
                    aU[m] = __builtin_amdgcn_mfma_f32_16x16x32_bf16(ax[m], wU, aU[m], 0, 0, 0);
                }
            }
            const int col = nt * 16 + l15;
            float bI = 0.f, bO = 0.f, bU = 0.f;
            if (col < MEMC) {
                bI = bix[col] + bih[col];
                bO = box_[col] + boh[col];
                bU = bux[col] + buh[col];
            }
#pragma unroll
            for (int m = 0; m < 4; ++m) {
#pragma unroll
                for (int r2 = 0; r2 < 4; ++r2) {
                    float ig = fsig(aI[m][r2] + bI);
                    float og = fsig(aO[m][r2] + bO);
                    float ug = ftanh_(aU[m][r2] + bU);
                    float cv = ig * ug;
                    cv_[m][r2] = cv;
                    hv_[m][r2] = og * ftanh_(cv);
                }
            }
        }
#pragma unroll
        for (int m = 0; m < 4; ++m) {
            __syncthreads();
            if (ntv) {
                const int cl = 16 * wv + l15;
#pragma unroll
                for (int r2 = 0; r2 < 4; ++r2) {
                    const int lr = 4 * lhi + r2;
                    chF[0][lr][cl] = cv_[m][r2];
                    chF[1][lr][cl] = hv_[m][r2];
                }
            }
            __syncthreads();
            const int c0 = 128 * k;
            const int colsK = (k == 2) ? 44 : 128;
            const int chunks = colsK >> 2;
            const int items = chunks << 4;          // 16 rows
            for (int t = tid; t < items; t += NTHR) {
                int lr = t / chunks, q = t - lr * chunks;
                int row = row0 + 16 * m + lr;
                int b = row >> (DDC - 1);
                int off = row & (L - 1);
                size_t o = ((size_t)b * NNC + base + off) * (size_t)MEMC + c0 + 4 * q;
                *reinterpret_cast<f32x4*>(&c[o]) =
                    *reinterpret_cast<const f32x4*>(&chF[0][lr][4 * q]);
                *reinterpret_cast<f32x4*>(&h[o]) =
                    *reinterpret_cast<const f32x4*>(&chF[1][lr][4 * q]);
            }
        }
    }
}

// ---------------------------------------------------------------------------
// Node: 32 rows/block. Streams: x-phase aI,aO,aU,aFX; h-phase via hs,h1:
//   aI,aO,aU,aFS (hs), aF1 (h1); f1=sig(aFX+aF1+bF), f2=sig(aFX+aFS-aF1+bF).
// Epilogue: stage iu,f1,f2,o (fp32) in LDS per 8-row half-pass, then
// cooperative coalesced float4 c1/c2 reads + c/h writes.
// kMode: 1 -> loop k=0..2 in-block; 0 -> k = blockIdx.y (small levels).
// ---------------------------------------------------------------------------
__global__ __launch_bounds__(512, 4)
void node_k(const float* __restrict__ embs,
            const float* __restrict__ bix, const float* __restrict__ bih,
            const float* __restrict__ bfx, const float* __restrict__ bfh,
            const float* __restrict__ box_, const float* __restrict__ boh,
            const float* __restrict__ bux, const float* __restrict__ buh,
            float* __restrict__ h, float* __restrict__ c,
            int lvl, int rowsTotal, int kMode)
{
    extern __shared__ __align__(16) unsigned char smd[];
    unsigned short* xs  = (unsigned short*)smd;
    unsigned short* hss = xs + NODE_M * KP;
    unsigned short* h1s = xs + 2 * NODE_M * KP;
    float (*gateF)[8][GP] = (float (*)[8][GP])(smd + (size_t)3 * NODE_M * KP * 2);

    const int L    = 1 << lvl;
    const int base = L - 1;
    const int tid  = threadIdx.x;
    const int row0 = blockIdx.x * NODE_M;

    for (int idx = tid; idx < NODE_M * 75; idx += NTHR) {
        int r = idx / 75, q = idx - 75 * r;
        int row = row0 + r;
        if (row < rowsTotal) {
            int b = row >> lvl;
            int off = row & (L - 1);
            int node = base + off;
            const float4 xv = *reinterpret_cast<const float4*>(
                &embs[((size_t)b * NNC + node) * IN_DIMC + 4 * q]);
            const float4 h1v = *reinterpret_cast<const float4*>(
                &h[((size_t)b * NNC + 2 * node + 1) * MEMC + 4 * q]);
            const float4 h2v = *reinterpret_cast<const float4*>(
                &h[((size_t)b * NNC + 2 * node + 2) * MEMC + 4 * q]);
            float4 hsv;
            hsv.x = h1v.x + h2v.x; hsv.y = h1v.y + h2v.y;
            hsv.z = h1v.z + h2v.z; hsv.w = h1v.w + h2v.w;
            *reinterpret_cast<ushort4*>(&xs [r * KP + 4 * q]) = f2bf4(xv);
            *reinterpret_cast<ushort4*>(&h1s[r * KP + 4 * q]) = f2bf4(h1v);
            *reinterpret_cast<ushort4*>(&hss[r * KP + 4 * q]) = f2bf4(hsv);
        } else {
            ushort4 z = make_ushort4(0, 0, 0, 0);
            *reinterpret_cast<ushort4*>(&xs [r * KP + 4 * q]) = z;
            *reinterpret_cast<ushort4*>(&h1s[r * KP + 4 * q]) = z;
            *reinterpret_cast<ushort4*>(&hss[r * KP + 4 * q]) = z;
        }
    }
    for (int idx = tid; idx < NODE_M * 7; idx += NTHR) {
        int r = idx / 7, qq = idx - 7 * r;
        ushort4 z = make_ushort4(0, 0, 0, 0);
        *reinterpret_cast<ushort4*>(&xs [r * KP + 300 + 4 * qq]) = z;
        *reinterpret_cast<ushort4*>(&h1s[r * KP + 300 + 4 * qq]) = z;
        *reinterpret_cast<ushort4*>(&hss[r * KP + 300 + 4 * qq]) = z;
    }
    __syncthreads();

    const int lane = tid & 63;
    const int l15  = lane & 15;
    const int lhi  = lane >> 4;
    const int wv   = tid >> 6;

    const int kBeg = kMode ? 0 : blockIdx.y;
    const int kEnd = kMode ? 3 : (int)blockIdx.y + 1;

    for (int k = kBeg; k < kEnd; ++k) {
        const int nt = 8 * k + wv;
        const bool ntv = (nt < NT_USED);
        f32x4 iu_[2], f1_[2], f2_[2], og_[2];
        if (ntv) {
            f32x4 aI[2], aO[2], aU[2], aFX[2], aFS[2], aF1[2];
            const f32x4 zv = {0.f, 0.f, 0.f, 0.f};
#pragma unroll
            for (int m = 0; m < 2; ++m) {
                aI[m] = zv; aO[m] = zv; aU[m] = zv;
                aFX[m] = zv; aFS[m] = zv; aF1[m] = zv;
            }
            // x-phase
#pragma unroll
            for (int kt = 0; kt < KT_N; ++kt) {
                bf16x8 ax[2];
#pragma unroll
                for (int m = 0; m < 2; ++m)
                    ax[m] = *reinterpret_cast<const bf16x8*>(
                        &xs[(16 * m + l15) * KP + kt * 32 + 8 * lhi]);
                const bf16x8 wI = *reinterpret_cast<const bf16x8*>(&g_Wp[0][kt][nt][lane][0]);
                const bf16x8 wF = *reinterpret_cast<const bf16x8*>(&g_Wp[2][kt][nt][lane][0]);
                const bf16x8 wO = *reinterpret_cast<const bf16x8*>(&g_Wp[4][kt][nt][lane][0]);
                const bf16x8 wU = *reinterpret_cast<const bf16x8*>(&g_Wp[6][kt][nt][lane][0]);
#pragma unroll
                for (int m = 0; m < 2; ++m) {
                    aI[m]  = __builtin_amdgcn_mfma_f32_16x16x32_bf16(ax[m], wI, aI[m],  0, 0, 0);
                    aFX[m] = __builtin_amdgcn_mfma_f32_16x16x32_bf16(ax[m], wF, aFX[m], 0, 0, 0);
                    aO[m]  = __builtin_amdgcn_mfma_f32_16x16x32_bf16(ax[m], wO, aO[m],  0, 0, 0);
                    aU[m]  = __builtin_amdgcn_mfma_f32_16x16x32_bf16(ax[m], wU, aU[m],  0, 0, 0);
                }
            }
            // h-phase (hs for i,o,u,fs; h1 for f1)
#pragma unroll
            for (int kt = 0; kt < KT_N; ++kt) {
                bf16x8 ahs[2], ah1[2];
#pragma unroll
                for (int m = 0; m < 2; ++m) {
                    ahs[m] = *reinterpret_cast<const bf16x8*>(
                        &hss[(16 * m + l15) * KP + kt * 32 + 8 * lhi]);
                    ah1[m] = *reinterpret_cast<const bf16x8*>(
                        &h1s[(16 * m + l15) * KP + kt * 32 + 8 * lhi]);
                }
                const bf16x8 wI = *reinterpret_cast<const bf16x8*>(&g_Wp[1][kt][nt][lane][0]);
                const bf16x8 wF = *reinterpret_cast<const bf16x8*>(&g_Wp[3][kt][nt][lane][0]);
                const bf16x8 wO = *reinterpret_cast<const bf16x8*>(&g_Wp[5][kt][nt][lane][0]);
                const bf16x8 wU = *reinterpret_cast<const bf16x8*>(&g_Wp[7][kt][nt][lane][0]);
#pragma unroll
                for (int m = 0; m < 2; ++m) {
                    aI[m]  = __builtin_amdgcn_mfma_f32_16x16x32_bf16(ahs[m], wI, aI[m],  0, 0, 0);
                    aO[m]  = __builtin_amdgcn_mfma_f32_16x16x32_bf16(ahs[m], wO, aO[m],  0, 0, 0);
                    aU[m]  = __builtin_amdgcn_mfma_f32_16x16x32_bf16(ahs[m], wU, aU[m],  0, 0, 0);
                    aFS[m] = __builtin_amdgcn_mfma_f32_16x16x32_bf16(ahs[m], wF, aFS[m], 0, 0, 0);
                    aF1[m] = __builtin_amdgcn_mfma_f32_16x16x32_bf16(ah1[m], wF, aF1[m], 0, 0, 0);
                }
            }
            const int col = nt * 16 + l15;
            float bI = 0.f, bO = 0.f, bU = 0.f, bF = 0.f;
            if (col < MEMC) {
                bI = bix[col] + bih[col];
                bO = box_[col] + boh[col];
                bU = bux[col] + buh[col];
                bF = bfx[col] + bfh[col];
            }
#pragma unroll
            for (int m = 0; m < 2; ++m) {
#pragma unroll
                for (int r2 = 0; r2 < 4; ++r2) {
                    float ig = fsig(aI[m][r2] + bI);
                    float og = fsig(aO[m][r2] + bO);
                    float ug = ftanh_(aU[m][r2] + bU);
                    iu_[m][r2] = ig * ug;
                    f1_[m][r2] = fsig(aFX[m][r2] + aF1[m][r2] + bF);
                    f2_[m][r2] = fsig(aFX[m][r2] + aFS[m][r2] - aF1[m][r2] + bF);
                    og_[m][r2] = og;
                }
            }
        }
        // 4 half-passes: (m, hh) over 8-row slices
#pragma unroll
        for (int p = 0; p < 4; ++p) {
            const int m = p >> 1, hh = p & 1;
            __syncthreads();
            if (ntv && ((lhi >> 1) == hh)) {
                const int cl = 16 * wv + l15;
                const int g1 = lhi & 1;
#pragma unroll
                for (int r2 = 0; r2 < 4; ++r2) {
                    const int lr = 4 * g1 + r2;
                    gateF[0][lr][cl] = iu_[m][r2];
                    gateF[1][lr][cl] = f1_[m][r2];
                    gateF[2][lr][cl] = f2_[m][r2];
                    gateF[3][lr][cl] = og_[m][r2];
                }
            }
            __syncthreads();
            const int c0 = 128 * k;
            const int colsK = (k == 2) ? 44 : 128;
            const int chunks = colsK >> 2;
            const int items = chunks << 3;          // 8 rows
            for (int t = tid; t < items; t += NTHR) {
                int lr = t / chunks, q = t - lr * chunks;
                int row = row0 + 16 * m + 8 * hh + lr;
                if (row < rowsTotal) {
                    int b = row >> lvl;
                    int off = row & (L - 1);
                    int node = base + off;
                    int col = c0 + 4 * q;
                    size_t o  = ((size_t)b * NNC + node) * (size_t)MEMC + col;
                    size_t o1 = ((size_t)b * NNC + 2 * node + 1) * (size_t)MEMC + col;
                    size_t o2 = ((size_t)b * NNC + 2 * node + 2) * (size_t)MEMC + col;
                    f32x4 iu4 = *reinterpret_cast<const f32x4*>(&gateF[0][lr][4 * q]);
                    f32x4 f14 = *reinterpret_cast<const f32x4*>(&gateF[1][lr][4 * q]);
                    f32x4 f24 = *reinterpret_cast<const f32x4*>(&gateF[2][lr][4 * q]);
                    f32x4 og4 = *reinterpret_cast<const f32x4*>(&gateF[3][lr][4 * q]);
                    f32x4 c14 = *reinterpret_cast<const f32x4*>(&c[o1]);
                    f32x4 c24 = *reinterpret_cast<const f32x4*>(&c[o2]);
                    f32x4 cn4, h4;
#pragma unroll
                    for (int j = 0; j < 4; ++j) {
                        float cn = iu4[j] + f14[j] * c14[j] + f24[j] * c24[j];
                        cn4[j] = cn;
                        h4[j] = og4[j] * ftanh_(cn);
                    }
                    *reinterpret_cast<f32x4*>(&c[o]) = cn4;
                    *reinterpret_cast<f32x4*>(&h[o]) = h4;
                }
            }
        }
    }
}

// ---------------------------------------------------------------------------
extern "C" void kernel_launch(void* const* d_in, const int* in_sizes, int n_in,
                              void* d_out, int out_size, void* d_ws, size_t ws_size,
                              hipStream_t stream)
{
    const float* embs = (const float*)d_in[0];
    const float* Wix  = (const float*)d_in[1];
    const float* bix  = (const float*)d_in[2];
    const float* Wih  = (const float*)d_in[3];
    const float* bih  = (const float*)d_in[4];
    const float* Wfx  = (const float*)d_in[5];
    const float* bfx  = (const float*)d_in[6];
    const float* Wfh  = (const float*)d_in[7];
    const float* bfh  = (const float*)d_in[8];
    const float* Wox  = (const float*)d_in[9];
    const float* box_ = (const float*)d_in[10];
    const float* Woh  = (const float*)d_in[11];
    const float* boh  = (const float*)d_in[12];
    const float* Wux  = (const float*)d_in[13];
    const float* bux  = (const float*)d_in[14];
    const float* Wuh  = (const float*)d_in[15];
    const float* buh  = (const float*)d_in[16];

    float* h = (float*)d_out;   // (B, N, 300) fp32
    float* c = (float*)d_ws;    // (B, N, 300) fp32 scratch

    const int nodeLds = 3 * NODE_M * KP * 2 + 4 * 8 * GP * 4;   // 62976+16896=79872
    (void)hipFuncSetAttribute((const void*)node_k,
                              hipFuncAttributeMaxDynamicSharedMemorySize, nodeLds);

    {   // pack weights to bf16 fragments
        const int total = 8 * KT_N * NT_PAD * 64;
        pack_w<<<(total + 255) / 256, 256, 0, stream>>>(Wix, Wih, Wfx, Wfh, Wox, Woh, Wux, Wuh);
    }

    {   // leaf level: 32768 rows / 64 = 512 blocks
        int rows = BBC << (DDC - 1);
        leaf_k<<<rows / LEAF_M, NTHR, 0, stream>>>(
            embs, bix, bih, box_, boh, bux, buh, h, c);
    }

    for (int lvl = DDC - 2; lvl >= 0; --lvl) {
        int rows = BBC << lvl;
        int blocksX = (rows + NODE_M - 1) / NODE_M;
        if (lvl >= 7) {
            node_k<<<dim3(blocksX, 1), NTHR, nodeLds, stream>>>(
                embs, bix, bih, bfx, bfh, box_, boh, bux, buh, h, c, lvl, rows, 1);
        } else {
            node_k<<<dim3(blocksX, 3), NTHR, nodeLds, stream>>>(
                embs, bix, bih, bfx, bfh, box_, boh, bux, buh, h, c, lvl, rows, 0);
        }
    }
}

// Round 7
// 483.412 us; speedup vs baseline: 4.3186x; 1.0572x over previous
//
#include <hip/hip_runtime.h>
#include <math.h>

#define IN_DIMC 300
#define MEMC    300
#define BBC     32
#define DDC     11
#define NNC     2047
#define KT_N    10          // K tiles of 32 (K padded 300->320)
#define NT_USED 19          // ceil(300/16)
#define NT_PAD  20
#define KP      328         // LDS row stride in bf16 elems (656B, 16B-aligned rows)
#define NODE_M  32
#define LEAF_M  64
#define NTHR    512
#define GP      132         // gate/out staging col stride (floats), bank-safe

typedef __attribute__((ext_vector_type(8))) short bf16x8;   // 8 bf16 = 4 VGPRs
typedef __attribute__((ext_vector_type(4))) float f32x4;

// Packed bf16 weight fragments: [w][kt][nt][lane][8]
__device__ __align__(16) unsigned short g_Wp[8][KT_N][NT_PAD][64][8];

__device__ __forceinline__ float fsig(float x)  { return 1.0f / (1.0f + __expf(-x)); }
__device__ __forceinline__ float ftanh_(float x){ return 2.0f / (1.0f + __expf(-2.0f * x)) - 1.0f; }
__device__ __forceinline__ unsigned short f2bf(float f) {   // RNE fp32 -> bf16
    unsigned int u = __float_as_uint(f);
    u += 0x7FFFu + ((u >> 16) & 1u);
    return (unsigned short)(u >> 16);
}
__device__ __forceinline__ ushort4 f2bf4(float4 v) {
    ushort4 r; r.x = f2bf(v.x); r.y = f2bf(v.y); r.z = f2bf(v.z); r.w = f2bf(v.w);
    return r;
}
#define WFRAG(w, kt, nt) (*reinterpret_cast<const bf16x8*>(&g_Wp[w][kt][nt][lane][0]))

// ---------------------------------------------------------------------------
// Pack 8 weight matrices (fp32 [K=300][N=300]) into bf16 B-fragment layout.
// WID: 0=ix 1=ih 2=fx 3=fh 4=ox 5=oh 6=ux 7=uh
// ---------------------------------------------------------------------------
__global__ void pack_w(const float* __restrict__ Wix, const float* __restrict__ Wih,
                       const float* __restrict__ Wfx, const float* __restrict__ Wfh,
                       const float* __restrict__ Wox, const float* __restrict__ Woh,
                       const float* __restrict__ Wux, const float* __restrict__ Wuh)
{
    int gid = blockIdx.x * blockDim.x + threadIdx.x;
    const int total = 8 * KT_N * NT_PAD * 64;
    if (gid >= total) return;
    int l  = gid & 63;
    int f  = gid >> 6;
    int nt = f % NT_PAD;
    int kt = (f / NT_PAD) % KT_N;
    int w  = f / (NT_PAD * KT_N);
    const float* Ws[8] = {Wix, Wih, Wfx, Wfh, Wox, Woh, Wux, Wuh};
    const float* src = Ws[w];
    int n  = nt * 16 + (l & 15);
    int k0 = kt * 32 + 8 * (l >> 4);
    unsigned short tmp[8];
#pragma unroll
    for (int i = 0; i < 8; ++i) {
        int k = k0 + i;
        float v = (n < MEMC && k < IN_DIMC) ? src[k * MEMC + n] : 0.0f;
        tmp[i] = f2bf(v);
    }
    *reinterpret_cast<uint4*>(&g_Wp[w][kt][nt][l][0]) = *reinterpret_cast<const uint4*>(tmp);
}

// ---------------------------------------------------------------------------
// Leaf: 64 rows/block, wave wv handles nt = 8k+wv (k=0..2).
// Weight fragments double-buffered (kt+1 issued before kt's MFMAs).
// ---------------------------------------------------------------------------
__global__ void __launch_bounds__(512) __attribute__((amdgpu_waves_per_eu(4, 4)))
leaf_k(const float* __restrict__ embs,
       const float* __restrict__ bix, const float* __restrict__ bih,
       const float* __restrict__ box_, const float* __restrict__ boh,
       const float* __restrict__ bux, const float* __restrict__ buh,
       float* __restrict__ h, float* __restrict__ c)
{
    __shared__ __align__(16) unsigned short xs[LEAF_M * KP];
    __shared__ __align__(16) float chF[2][16][GP];

    const int L    = 1 << (DDC - 1);
    const int base = L - 1;
    const int tid  = threadIdx.x;
    const int row0 = blockIdx.x * LEAF_M;

    for (int idx = tid; idx < LEAF_M * 75; idx += NTHR) {
        int r = idx / 75, q = idx - 75 * r;
        int row = row0 + r;
        int b = row >> (DDC - 1);
        int off = row & (L - 1);
        const float4 v = *reinterpret_cast<const float4*>(
            &embs[((size_t)b * NNC + base + off) * IN_DIMC + 4 * q]);
        *reinterpret_cast<ushort4*>(&xs[r * KP + 4 * q]) = f2bf4(v);
    }
    for (int idx = tid; idx < LEAF_M * 7; idx += NTHR) {
        int r = idx / 7, qq = idx - 7 * r;
        *reinterpret_cast<ushort4*>(&xs[r * KP + 300 + 4 * qq]) = make_ushort4(0, 0, 0, 0);
    }
    __syncthreads();

    const int lane = tid & 63;
    const int l15  = lane & 15;
    const int lhi  = lane >> 4;
    const int wv   = tid >> 6;

    for (int k = 0; k < 3; ++k) {
        const int nt = 8 * k + wv;
        const bool ntv = (nt < NT_USED);
        f32x4 cv_[4], hv_[4];
        if (ntv) {
            f32x4 aI[4], aO[4], aU[4];
            const f32x4 zv = {0.f, 0.f, 0.f, 0.f};
#pragma unroll
            for (int m = 0; m < 4; ++m) { aI[m] = zv; aO[m] = zv; aU[m] = zv; }

            bf16x8 cI = WFRAG(0, 0, nt), cO = WFRAG(4, 0, nt), cU = WFRAG(6, 0, nt);
#pragma unroll
            for (int kt = 0; kt < KT_N; ++kt) {
                bf16x8 nI = cI, nO = cO, nU = cU;
                if (kt + 1 < KT_N) {
                    nI = WFRAG(0, kt + 1, nt);
                    nO = WFRAG(4, kt + 1, nt);
                    nU = WFRAG(6, kt + 1, nt);
                }
                bf16x8 ax[4];
#pragma unroll
                for (int m = 0; m < 4; ++m)
                    ax[m] = *reinterpret_cast<const bf16x8*>(
                        &xs[(16 * m + l15) * KP + kt * 32 + 8 * lhi]);
#pragma unroll
                for (int m = 0; m < 4; ++m) {
                    aI[m] = __builtin_amdgcn_mfma_f32_16x16x32_bf16(ax[m], cI, aI[m], 0, 0, 0);
                    aO[m] = __builtin_amdgcn_mfma_f32_16x16x32_bf16(ax[m], cO, aO[m], 0, 0, 0);
                    aU[m] = __builtin_amdgcn_mfma_f32_16x16x32_bf16(ax[m], cU, aU[m], 0, 0, 0);
                }
                cI = nI; cO = nO; cU = nU;
            }
            const int col = nt * 16 + l15;
            float bI = 0.f, bO = 0.f, bU = 0.f;
            if (col < MEMC) {
                bI = bix[col] + bih[col];
                bO = box_[col] + boh[col];
                bU = bux[col] + buh[col];
            }
#pragma unroll
            for (int m = 0; m < 4; ++m) {
#pragma unroll
                for (int r2 = 0; r2 < 4; ++r2) {
                    float ig = fsig(aI[m][r2] + bI);
                    float og = fsig(aO[m][r2] + bO);
                    float ug = ftanh_(aU[m][r2] + bU);
                    float cv = ig * ug;
                    cv_[m][r2] = cv;
                    hv_[m][r2] = og * ftanh_(cv);
                }
            }
        }
#pragma unroll
        for (int m = 0; m < 4; ++m) {
            __syncthreads();
            if (ntv) {
                const int cl = 16 * wv + l15;
#pragma unroll
                for (int r2 = 0; r2 < 4; ++r2) {
                    const int lr = 4 * lhi + r2;
                    chF[0][lr][cl] = cv_[m][r2];
                    chF[1][lr][cl] = hv_[m][r2];
                }
            }
            __syncthreads();
            const int c0 = 128 * k;
            const int colsK = (k == 2) ? 44 : 128;
            const int chunks = colsK >> 2;
            const int items = chunks << 4;          // 16 rows
            for (int t = tid; t < items; t += NTHR) {
                int lr = t / chunks, q = t - lr * chunks;
                int row = row0 + 16 * m + lr;
                int b = row >> (DDC - 1);
                int off = row & (L - 1);
                size_t o = ((size_t)b * NNC + base + off) * (size_t)MEMC + c0 + 4 * q;
                *reinterpret_cast<f32x4*>(&c[o]) =
                    *reinterpret_cast<const f32x4*>(&chF[0][lr][4 * q]);
                *reinterpret_cast<f32x4*>(&h[o]) =
                    *reinterpret_cast<const f32x4*>(&chF[1][lr][4 * q]);
            }
        }
    }
}

// ---------------------------------------------------------------------------
// Node: 32 rows/block. x-phase aI,aO,aU,aFX; h-phase aI,aO,aU,aFS (hs), aF1 (h1).
// f1=sig(aFX+aF1+bF), f2=sig(aFX+aFS-aF1+bF). Weight fragments double-buffered.
// kMode: 1 -> loop k=0..2 in-block; 0 -> k = blockIdx.y.
// ---------------------------------------------------------------------------
__global__ void __launch_bounds__(512) __attribute__((amdgpu_waves_per_eu(4, 4)))
node_k(const float* __restrict__ embs,
       const float* __restrict__ bix, const float* __restrict__ bih,
       const float* __restrict__ bfx, const float* __restrict__ bfh,
       const float* __restrict__ box_, const float* __restrict__ boh,
       const float* __restrict__ bux, const float* __restrict__ buh,
       float* __restrict__ h, float* __restrict__ c,
       int lvl, int rowsTotal, int kMode)
{
    extern __shared__ __align__(16) unsigned char smd[];
    unsigned short* xs  = (unsigned short*)smd;
    unsigned short* hss = xs + NODE_M * KP;
    unsigned short* h1s = xs + 2 * NODE_M * KP;
    float (*gateF)[8][GP] = (float (*)[8][GP])(smd + (size_t)3 * NODE_M * KP * 2);

    const int L    = 1 << lvl;
    const int base = L - 1;
    const int tid  = threadIdx.x;
    const int row0 = blockIdx.x * NODE_M;

    for (int idx = tid; idx < NODE_M * 75; idx += NTHR) {
        int r = idx / 75, q = idx - 75 * r;
        int row = row0 + r;
        if (row < rowsTotal) {
            int b = row >> lvl;
            int off = row & (L - 1);
            int node = base + off;
            const float4 xv = *reinterpret_cast<const float4*>(
                &embs[((size_t)b * NNC + node) * IN_DIMC + 4 * q]);
            const float4 h1v = *reinterpret_cast<const float4*>(
                &h[((size_t)b * NNC + 2 * node + 1) * MEMC + 4 * q]);
            const float4 h2v = *reinterpret_cast<const float4*>(
                &h[((size_t)b * NNC + 2 * node + 2) * MEMC + 4 * q]);
            float4 hsv;
            hsv.x = h1v.x + h2v.x; hsv.y = h1v.y + h2v.y;
            hsv.z = h1v.z + h2v.z; hsv.w = h1v.w + h2v.w;
            *reinterpret_cast<ushort4*>(&xs [r * KP + 4 * q]) = f2bf4(xv);
            *reinterpret_cast<ushort4*>(&h1s[r * KP + 4 * q]) = f2bf4(h1v);
            *reinterpret_cast<ushort4*>(&hss[r * KP + 4 * q]) = f2bf4(hsv);
        } else {
            ushort4 z = make_ushort4(0, 0, 0, 0);
            *reinterpret_cast<ushort4*>(&xs [r * KP + 4 * q]) = z;
            *reinterpret_cast<ushort4*>(&h1s[r * KP + 4 * q]) = z;
            *reinterpret_cast<ushort4*>(&hss[r * KP + 4 * q]) = z;
        }
    }
    for (int idx = tid; idx < NODE_M * 7; idx += NTHR) {
        int r = idx / 7, qq = idx - 7 * r;
        ushort4 z = make_ushort4(0, 0, 0, 0);
        *reinterpret_cast<ushort4*>(&xs [r * KP + 300 + 4 * qq]) = z;
        *reinterpret_cast<ushort4*>(&h1s[r * KP + 300 + 4 * qq]) = z;
        *reinterpret_cast<ushort4*>(&hss[r * KP + 300 + 4 * qq]) = z;
    }
    __syncthreads();

    const int lane = tid & 63;
    const int l15  = lane & 15;
    const int lhi  = lane >> 4;
    const int wv   = tid >> 6;

    const int kBeg = kMode ? 0 : blockIdx.y;
    const int kEnd = kMode ? 3 : (int)blockIdx.y + 1;

    for (int k = kBeg; k < kEnd; ++k) {
        const int nt = 8 * k + wv;
        const bool ntv = (nt < NT_USED);
        f32x4 iu_[2], f1_[2], f2_[2], og_[2];
        if (ntv) {
            f32x4 aI[2], aO[2], aU[2], aFX[2], aFS[2], aF1[2];
            const f32x4 zv = {0.f, 0.f, 0.f, 0.f};
#pragma unroll
            for (int m = 0; m < 2; ++m) {
                aI[m] = zv; aO[m] = zv; aU[m] = zv;
                aFX[m] = zv; aFS[m] = zv; aF1[m] = zv;
            }
            // x-phase (double-buffered weights)
            {
                bf16x8 cI = WFRAG(0, 0, nt), cF = WFRAG(2, 0, nt);
                bf16x8 cO = WFRAG(4, 0, nt), cU = WFRAG(6, 0, nt);
#pragma unroll
                for (int kt = 0; kt < KT_N; ++kt) {
                    bf16x8 nI = cI, nF = cF, nO = cO, nU = cU;
                    if (kt + 1 < KT_N) {
                        nI = WFRAG(0, kt + 1, nt);
                        nF = WFRAG(2, kt + 1, nt);
                        nO = WFRAG(4, kt + 1, nt);
                        nU = WFRAG(6, kt + 1, nt);
                    }
                    bf16x8 ax[2];
#pragma unroll
                    for (int m = 0; m < 2; ++m)
                        ax[m] = *reinterpret_cast<const bf16x8*>(
                            &xs[(16 * m + l15) * KP + kt * 32 + 8 * lhi]);
#pragma unroll
                    for (int m = 0; m < 2; ++m) {
                        aI[m]  = __builtin_amdgcn_mfma_f32_16x16x32_bf16(ax[m], cI, aI[m],  0, 0, 0);
                        aFX[m] = __builtin_amdgcn_mfma_f32_16x16x32_bf16(ax[m], cF, aFX[m], 0, 0, 0);
                        aO[m]  = __builtin_amdgcn_mfma_f32_16x16x32_bf16(ax[m], cO, aO[m],  0, 0, 0);
                        aU[m]  = __builtin_amdgcn_mfma_f32_16x16x32_bf16(ax[m], cU, aU[m],  0, 0, 0);
                    }
                    cI = nI; cF = nF; cO = nO; cU = nU;
                }
            }
            // h-phase (double-buffered weights)
            {
                bf16x8 cI = WFRAG(1, 0, nt), cF = WFRAG(3, 0, nt);
                bf16x8 cO = WFRAG(5, 0, nt), cU = WFRAG(7, 0, nt);
#pragma unroll
                for (int kt = 0; kt < KT_N; ++kt) {
                    bf16x8 nI = cI, nF = cF, nO = cO, nU = cU;
                    if (kt + 1 < KT_N) {
                        nI = WFRAG(1, kt + 1, nt);
                        nF = WFRAG(3, kt + 1, nt);
                        nO = WFRAG(5, kt + 1, nt);
                        nU = WFRAG(7, kt + 1, nt);
                    }
                    bf16x8 ahs[2], ah1[2];
#pragma unroll
                    for (int m = 0; m < 2; ++m) {
                        ahs[m] = *reinterpret_cast<const bf16x8*>(
                            &hss[(16 * m + l15) * KP + kt * 32 + 8 * lhi]);
                        ah1[m] = *reinterpret_cast<const bf16x8*>(
                            &h1s[(16 * m + l15) * KP + kt * 32 + 8 * lhi]);
                    }
#pragma unroll
                    for (int m = 0; m < 2; ++m) {
                        aI[m]  = __builtin_amdgcn_mfma_f32_16x16x32_bf16(ahs[m], cI, aI[m],  0, 0, 0);
                        aO[m]  = __builtin_amdgcn_mfma_f32_16x16x32_bf16(ahs[m], cO, aO[m],  0, 0, 0);
                        aU[m]  = __builtin_amdgcn_mfma_f32_16x16x32_bf16(ahs[m], cU, aU[m],  0, 0, 0);
                        aFS[m] = __builtin_amdgcn_mfma_f32_16x16x32_bf16(ahs[m], cF, aFS[m], 0, 0, 0);
                        aF1[m] = __builtin_amdgcn_mfma_f32_16x16x32_bf16(ah1[m], cF, aF1[m], 0, 0, 0);
                    }
                    cI = nI; cF = nF; cO = nO; cU = nU;
                }
            }
            const int col = nt * 16 + l15;
            float bI = 0.f, bO = 0.f, bU = 0.f, bF = 0.f;
            if (col < MEMC) {
                bI = bix[col] + bih[col];
                bO = box_[col] + boh[col];
                bU = bux[col] + buh[col];
                bF = bfx[col] + bfh[col];
            }
#pragma unroll
            for (int m = 0; m < 2; ++m) {
#pragma unroll
                for (int r2 = 0; r2 < 4; ++r2) {
                    float ig = fsig(aI[m][r2] + bI);
                    float og = fsig(aO[m][r2] + bO);
                    float ug = ftanh_(aU[m][r2] + bU);
                    iu_[m][r2] = ig * ug;
                    f1_[m][r2] = fsig(aFX[m][r2] + aF1[m][r2] + bF);
                    f2_[m][r2] = fsig(aFX[m][r2] + aFS[m][r2] - aF1[m][r2] + bF);
                    og_[m][r2] = og;
                }
            }
        }
        // 4 half-passes: (m, hh) over 8-row slices
#pragma unroll
        for (int p = 0; p < 4; ++p) {
            const int m = p >> 1, hh = p & 1;
            __syncthreads();
            if (ntv && ((lhi >> 1) == hh)) {
                const int cl = 16 * wv + l15;
                const int g1 = lhi & 1;
#pragma unroll
                for (int r2 = 0; r2 < 4; ++r2) {
                    const int lr = 4 * g1 + r2;
                    gateF[0][lr][cl] = iu_[m][r2];
                    gateF[1][lr][cl] = f1_[m][r2];
                    gateF[2][lr][cl] = f2_[m][r2];
                    gateF[3][lr][cl] = og_[m][r2];
                }
            }
            __syncthreads();
            const int c0 = 128 * k;
            const int colsK = (k == 2) ? 44 : 128;
            const int chunks = colsK >> 2;
            const int items = chunks << 3;          // 8 rows
            for (int t = tid; t < items; t += NTHR) {
                int lr = t / chunks, q = t - lr * chunks;
                int row = row0 + 16 * m + 8 * hh + lr;
                if (row < rowsTotal) {
                    int b = row >> lvl;
                    int off = row & (L - 1);
                    int node = base + off;
                    int col = c0 + 4 * q;
                    size_t o  = ((size_t)b * NNC + node) * (size_t)MEMC + col;
                    size_t o1 = ((size_t)b * NNC + 2 * node + 1) * (size_t)MEMC + col;
                    size_t o2 = ((size_t)b * NNC + 2 * node + 2) * (size_t)MEMC + col;
                    f32x4 iu4 = *reinterpret_cast<const f32x4*>(&gateF[0][lr][4 * q]);
                    f32x4 f14 = *reinterpret_cast<const f32x4*>(&gateF[1][lr][4 * q]);
                    f32x4 f24 = *reinterpret_cast<const f32x4*>(&gateF[2][lr][4 * q]);
                    f32x4 og4 = *reinterpret_cast<const f32x4*>(&gateF[3][lr][4 * q]);
                    f32x4 c14 = *reinterpret_cast<const f32x4*>(&c[o1]);
                    f32x4 c24 = *reinterpret_cast<const f32x4*>(&c[o2]);
                    f32x4 cn4, h4;
#pragma unroll
                    for (int j = 0; j < 4; ++j) {
                        float cn = iu4[j] + f14[j] * c14[j] + f24[j] * c24[j];
                        cn4[j] = cn;
                        h4[j] = og4[j] * ftanh_(cn);
                    }
                    *reinterpret_cast<f32x4*>(&c[o]) = cn4;
                    *reinterpret_cast<f32x4*>(&h[o]) = h4;
                }
            }
        }
    }
}

// ---------------------------------------------------------------------------
extern "C" void kernel_launch(void* const* d_in, const int* in_sizes, int n_in,
                              void* d_out, int out_size, void* d_ws, size_t ws_size,
                              hipStream_t stream)
{
    const float* embs = (const float*)d_in[0];
    const float* Wix  = (const float*)d_in[1];
    const float* bix  = (const float*)d_in[2];
    const float* Wih  = (const float*)d_in[3];
    const float* bih  = (const float*)d_in[4];
    const float* Wfx  = (const float*)d_in[5];
    const float* bfx  = (const float*)d_in[6];
    const float* Wfh  = (const float*)d_in[7];
    const float* bfh  = (const float*)d_in[8];
    const float* Wox  = (const float*)d_in[9];
    const float* box_ = (const float*)d_in[10];
    const float* Woh  = (const float*)d_in[11];
    const float* boh  = (const float*)d_in[12];
    const float* Wux  = (const float*)d_in[13];
    const float* bux  = (const float*)d_in[14];
    const float* Wuh  = (const float*)d_in[15];
    const float* buh  = (const float*)d_in[16];

    float* h = (float*)d_out;   // (B, N, 300) fp32
    float* c = (float*)d_ws;    // (B, N, 300) fp32 scratch

    const int nodeLds = 3 * NODE_M * KP * 2 + 4 * 8 * GP * 4;   // 79,872 B
    (void)hipFuncSetAttribute((const void*)node_k,
                              hipFuncAttributeMaxDynamicSharedMemorySize, nodeLds);

    {   // pack weights to bf16 fragments
        const int total = 8 * KT_N * NT_PAD * 64;
        pack_w<<<(total + 255) / 256, 256, 0, stream>>>(Wix, Wih, Wfx, Wfh, Wox, Woh, Wux, Wuh);
    }

    {   // leaf level: 32768 rows / 64 = 512 blocks
        int rows = BBC << (DDC - 1);
        leaf_k<<<rows / LEAF_M, NTHR, 0, stream>>>(
            embs, bix, bih, box_, boh, bux, buh, h, c);
    }

    for (int lvl = DDC - 2; lvl >= 0; --lvl) {
        int rows = BBC << lvl;
        int blocksX = (rows + NODE_M - 1) / NODE_M;
        if (blocksX >= 512) {
            // 2 blocks/CU already: loop k in-block (amortize staging)
            node_k<<<dim3(blocksX, 1), NTHR, nodeLds, stream>>>(
                embs, bix, bih, bfx, bfh, box_, boh, bux, buh, h, c, lvl, rows, 1);
        } else {
            // split columns across blockIdx.y for concurrency
            node_k<<<dim3(blocksX, 3), NTHR, nodeLds, stream>>>(
                embs, bix, bih, bfx, bfh, box_, boh, bux, buh, h, c, lvl, rows, 0);
        }
    }
}